// Round 15
// baseline (828.271 us; speedup 1.0000x reference)
//
#include <hip/hip_runtime.h>
#include <math.h>

#define B_    16
#define NP_   64
#define J_    17
#define C_    480
#define H_    128
#define W_    128
#define L_    4
#define HW_   (H_ * W_)
#define NSAMP (B_ * NP_)      // 1024
#define MROWS (NSAMP * J_)    // 17408
#define EPS_  1e-5f
#define NMAT  (1 + 2 * L_)    // 9 graph-conv weight matrices
#define NPAD  512             // weight N padded to 512 rows for maskless staging
#define TC    96              // transpose tile: channels
#define TS    64              // transpose tile: spatial
#define NT_   (256 * 5 * B_)  // 20480 transpose tiles
#define NW_   11520           // wsplit blocks
#define PSTR  133             // Y-panel row stride (f32), %32=5 -> <=2-way bank conflicts

typedef __attribute__((ext_vector_type(8))) short bf16x8;
typedef __attribute__((ext_vector_type(4))) short bf16x4;
typedef __attribute__((ext_vector_type(4))) float f32x4;

__device__ __forceinline__ unsigned short f2bf(float f) {
    unsigned int u = __float_as_uint(f);
    unsigned int r = (u + 0x7fffu + ((u >> 16) & 1u)) >> 16;
    return (unsigned short)r;
}
__device__ __forceinline__ float bf2f(unsigned short h) {
    return __uint_as_float(((unsigned int)h) << 16);
}

// async global->LDS, 16B per lane; LDS dest = wave-uniform base + lane*16
#define GLD16(gsrc, ldst)                                                                 \
    __builtin_amdgcn_global_load_lds((const __attribute__((address_space(1))) void*)(gsrc), \
                                     (__attribute__((address_space(3))) void*)(ldst), 16, 0, 0)

// ---------------- merged prep: NCHW->NHWC bf16 transpose + weight split ----------------
__global__ __launch_bounds__(256) void k_prep(const float* __restrict__ feat,
                                              const float* __restrict__ Wh,
                                              const float* __restrict__ Wres,
                                              const float* __restrict__ Wp1,
                                              short* __restrict__ nhwc,
                                              short* __restrict__ WtH,
                                              short* __restrict__ WpH) {
    int bid = blockIdx.x;
    int tid = threadIdx.x;
    if (bid < NT_) {
        __shared__ float t[TC][73];
        int sb = bid & 255;
        int cb = (bid >> 8) % 5;
        int b  = bid / 1280;
        int c0 = cb * TC, s0 = sb * TS;
        const float* src = feat + ((size_t)b * C_ + c0) * HW_ + s0;
        #pragma unroll
        for (int i = 0; i < 6; ++i) {
            int f  = tid + i * 256;
            int c  = f >> 4;
            int sq = (f & 15) * 4;
            float4 v = *reinterpret_cast<const float4*>(src + (size_t)c * HW_ + sq);
            t[c][sq + 0] = v.x;
            t[c][sq + 1] = v.y;
            t[c][sq + 2] = v.z;
            t[c][sq + 3] = v.w;
        }
        __syncthreads();
        int sy = tid >> 2;
        int cx = (tid & 3) * (TC / 4);
        short* dst = nhwc + ((size_t)b * HW_ + s0 + sy) * C_ + c0 + cx;
        alignas(16) unsigned short tmp[TC / 4];
        #pragma unroll
        for (int i = 0; i < TC / 4; ++i) tmp[i] = f2bf(t[cx + i][sy]);
        #pragma unroll
        for (int i = 0; i < 3; ++i)
            *reinterpret_cast<uint4*>(dst + i * 8) = *reinterpret_cast<const uint4*>(tmp + i * 8);
    } else {
        int gid = (bid - NT_) * 256 + tid;
        const int t1 = NMAT * NPAD * C_;
        const int t2 = NPAD * 3 * C_;
        if (gid < t1) {
            int m   = gid / (NPAD * C_);
            int rem = gid % (NPAD * C_);
            int n = rem / C_;
            int k = rem % C_;
            float v = 0.f;
            if (n < C_) {
                const float* src = (m == 0) ? Wh : (Wres + (size_t)(m - 1) * C_ * C_);
                v = src[(size_t)k * C_ + n];
            }
            WtH[gid] = (short)f2bf(v);
        } else if (gid < t1 + t2) {
            int g2 = gid - t1;
            int n = g2 / (3 * C_);
            int k = g2 % (3 * C_);
            float v = (n < C_) ? Wp1[(size_t)n * 3 * C_ + k] : 0.f;
            WpH[g2] = (short)f2bf(v);
        }
    }
}

// ---------------- bilinear gather (NHWC bf16) -> sampled X bf16 [MROWS][C] (no mix) ----------------
__global__ __launch_bounds__(256) void k_gather(const short* __restrict__ nhwc,
                                                const float* __restrict__ coords,
                                                short* __restrict__ Xs) {
    __shared__ float sw[J_][4];
    __shared__ int   si[J_];
    int n = blockIdx.x;
    int b = n / NP_;
    if (threadIdx.x < J_) {
        int j = threadIdx.x;
        int p = n * J_ + j;
        float x = coords[p * 2 + 0];
        float y = coords[p * 2 + 1];
        float x0f = fminf(fmaxf(floorf(x), 0.f), (float)(W_ - 2));
        float y0f = fminf(fmaxf(floorf(y), 0.f), (float)(H_ - 2));
        float wx = x - x0f, wy = y - y0f;
        sw[j][0] = (1.f - wx) * (1.f - wy);
        sw[j][1] = wx * (1.f - wy);
        sw[j][2] = (1.f - wx) * wy;
        sw[j][3] = wx * wy;
        si[j] = (int)y0f * W_ + (int)x0f;
    }
    __syncthreads();
    const short* base = nhwc + (size_t)b * HW_ * C_;
    for (int idx = threadIdx.x; idx < J_ * (C_ / 8); idx += 256) {
        int j  = idx / (C_ / 8);
        int c8 = (idx - j * (C_ / 8)) * 8;
        const short* p00 = base + (size_t)si[j] * C_ + c8;
        bf16x8 v00 = *reinterpret_cast<const bf16x8*>(p00);
        bf16x8 v01 = *reinterpret_cast<const bf16x8*>(p00 + C_);
        bf16x8 v10 = *reinterpret_cast<const bf16x8*>(p00 + W_ * C_);
        bf16x8 v11 = *reinterpret_cast<const bf16x8*>(p00 + W_ * C_ + C_);
        float w0 = sw[j][0], w1 = sw[j][1], w2 = sw[j][2], w3 = sw[j][3];
        bf16x8 o;
        #pragma unroll
        for (int e = 0; e < 8; ++e) {
            float v = bf2f((unsigned short)v00[e]) * w0 +
                      bf2f((unsigned short)v01[e]) * w1 +
                      bf2f((unsigned short)v10[e]) * w2 +
                      bf2f((unsigned short)v11[e]) * w3;
            o[e] = (short)f2bf(v);
        }
        *reinterpret_cast<bf16x8*>(Xs + ((size_t)n * J_ + j) * C_ + c8) = o;
    }
}

// ---------------- fused GEMM+mix: Z = relu(bn(adj @ (X@W) + bias)) (+res) ----------------
// Tile: 68 rows (4 whole samples, staged 80) x 128 cols. 4 waves, wave w = cols w*32..w*32+31.
// k-loop: gload_lds 13 slices/buffer (A:5, B:8), XOR swizzle, 2-phase double buffer.
// Epilogue: acc -> f32 LDS panel [80][PSTR] -> per-(sample,col) 17x17 adj mix -> bn/relu(+res).
template <bool ADD>
__global__ __launch_bounds__(256) void k_fgemm(const short* __restrict__ X,
                                               const short* __restrict__ Bm,
                                               const float* __restrict__ adj,
                                               const float* __restrict__ bias,
                                               const float* __restrict__ bn4,
                                               const short* res,   // may alias out
                                               short* out,
                                               int K) {
    __shared__ __align__(16) char smem[80 * PSTR * 4];   // 42560 B: k-bufs (2x13312) U Y-panel
    __shared__ float sadj[J_ * J_];

    int nwg = gridDim.x * gridDim.y;      // 1024
    int lin = blockIdx.y * gridDim.x + blockIdx.x;
    int cpx = nwg >> 3;
    int swz = (lin & 7) * cpx + (lin >> 3);
    const int rb   = swz / gridDim.x;     // 0..255
    const int cb   = swz % gridDim.x;     // 0..3
    const int row0 = rb * 68;
    const int col0 = cb * 128;

    const int tid  = threadIdx.x;
    const int lane = tid & 63;
    const int wid  = tid >> 6;
    const int wn0  = wid * 32;            // wave col offset
    const int kq   = lane >> 4;
    const int fr   = lane & 15;

    for (int t = tid; t < J_ * J_; t += 256) sadj[t] = adj[t];

    f32x4 acc[5][2];
    #pragma unroll
    for (int i = 0; i < 5; i++)
        #pragma unroll
        for (int j = 0; j < 2; j++) acc[i][j] = (f32x4){0.f, 0.f, 0.f, 0.f};

    // slice assignment: wave0 -> slices 0-3, wave1 -> 4-6, wave2 -> 7-9, wave3 -> 10-12
    // slices 0-4 = A rows sl*16..; slices 5-12 = B rows (sl-5)*16..
    const short* psrc[4];
    int lof[4];
    #pragma unroll
    for (int t = 0; t < 4; ++t) {
        int sl = (wid == 0) ? t : (1 + 3 * wid + t);
        if (sl > 12) sl = 12;
        int isA  = (sl < 5);
        int prel = (isA ? sl : sl - 5) * 1024 + lane * 16;
        int v = prel >> 6;
        int r = v ^ ((v >> 2) & 1);
        int cq = ((prel >> 4) & 3) ^ (r & 3);
        psrc[t] = isA ? (X + (size_t)(row0 + r) * K + cq * 8)
                      : (Bm + (size_t)(col0 + r) * K + cq * 8);
        lof[t] = sl * 1024;
    }

    const int NS = K / 32;
    {   // prologue: stage tile 0 into buf 0
        char* lb = smem;
        #pragma unroll
        for (int t = 0; t < 4; ++t)
            if (t < 3 || wid == 0) GLD16(psrc[t], lb + lof[t]);
    }
    __syncthreads();

    for (int ks = 0; ks < NS; ++ks) {
        if (ks + 1 < NS) {
            const int kk = (ks + 1) * 32;
            char* lb = smem + ((ks + 1) & 1) * 13312;
            #pragma unroll
            for (int t = 0; t < 4; ++t)
                if (t < 3 || wid == 0) GLD16(psrc[t] + kk, lb + lof[t]);
        }
        const short* lbc = (const short*)(smem + (ks & 1) * 13312);
        bf16x8 fa[5], fb[2];
        #pragma unroll
        for (int mf = 0; mf < 5; ++mf) {
            int r  = mf * 16 + fr;
            int so = ((r * 64 + kq * 16) ^ ((r & 7) << 4)) >> 1;
            fa[mf] = *reinterpret_cast<const bf16x8*>(lbc + so);
        }
        #pragma unroll
        for (int nf = 0; nf < 2; ++nf) {
            int r  = wn0 + nf * 16 + fr;
            int so = ((r * 64 + kq * 16) ^ ((r & 7) << 4)) >> 1;
            fb[nf] = *reinterpret_cast<const bf16x8*>(lbc + 2560 + so);   // B region at 5120 B
        }
        __builtin_amdgcn_s_setprio(1);
        #pragma unroll
        for (int mf = 0; mf < 5; ++mf)
            #pragma unroll
            for (int nf = 0; nf < 2; ++nf)
                acc[mf][nf] = __builtin_amdgcn_mfma_f32_16x16x32_bf16(fa[mf], fb[nf], acc[mf][nf], 0, 0, 0);
        __builtin_amdgcn_s_setprio(0);
        __syncthreads();   // drains prefetch + guards buffer reuse
    }

    // ---- write Y (f32) to panel; C/D layout col=lane&15, row=(lane>>4)*4+reg ----
    float* panel = (float*)smem;
    const int rq = lane >> 4;
    #pragma unroll
    for (int mf = 0; mf < 5; ++mf)
        #pragma unroll
        for (int nf = 0; nf < 2; ++nf) {
            int colp = wn0 + nf * 16 + fr;
            int rowp = mf * 16 + rq * 4;
            #pragma unroll
            for (int rr = 0; rr < 4; ++rr)
                panel[(rowp + rr) * PSTR + colp] = acc[mf][nf][rr];
        }
    __syncthreads();

    // ---- mix + bias + BN + ReLU (+res), write bf16 ----
    for (int wi = tid; wi < 512; wi += 256) {
        int si = wi >> 7;          // sample 0..3
        int c  = wi & 127;
        int col = col0 + c;
        if (col >= C_) continue;
        float ys[J_];
        #pragma unroll
        for (int j = 0; j < J_; ++j) ys[j] = panel[(si * J_ + j) * PSTR + c];
        float bia = bias[col];
        float g  = bn4[col];
        float be = bn4[C_ + col];
        float mu = bn4[2 * C_ + col];
        float va = bn4[3 * C_ + col];
        float sc = rsqrtf(va + EPS_) * g;
        size_t gbase = (size_t)(row0 + si * J_) * C_ + col;
        #pragma unroll
        for (int j = 0; j < J_; ++j) {
            float s = 0.f;
            #pragma unroll
            for (int k = 0; k < J_; ++k) s = fmaf(sadj[j * J_ + k], ys[k], s);
            float v = (s + bia - mu) * sc + be;
            v = fmaxf(v, 0.f);
            if (ADD) v += bf2f((unsigned short)res[gbase + (size_t)j * C_]);
            out[gbase + (size_t)j * C_] = (short)f2bf(v);
        }
    }
}

// ---------------- plain 1-term bf16 MFMA GEMM (R14-proven, BM=64) — pred layer only ----------------
template <bool ADD>
__global__ __launch_bounds__(256) void k_gemm_mfma(const short* __restrict__ A,
                                                   const short* __restrict__ Bm,
                                                   const float* __restrict__ bias,
                                                   const float* __restrict__ bn4,
                                                   const short* res,
                                                   short* out,
                                                   int M, int N, int K) {
    __shared__ short lds[2 * 6144];

    int nwg = gridDim.x * gridDim.y;
    int lin = blockIdx.y * gridDim.x + blockIdx.x;
    int cpx = nwg >> 3;
    int swz = (lin & 7) * cpx + (lin >> 3);
    const int row0 = (swz / gridDim.x) * 64;
    const int col0 = (swz % gridDim.x) * 128;

    const int tid  = threadIdx.x;
    const int lane = tid & 63;
    const int wid  = tid >> 6;
    const int wm0  = (wid >> 1) * 32;
    const int wn0  = (wid & 1) * 64;

    f32x4 acc[2][4];
    #pragma unroll
    for (int i = 0; i < 2; i++)
        #pragma unroll
        for (int j = 0; j < 4; j++) acc[i][j] = (f32x4){0.f, 0.f, 0.f, 0.f};

    const int kq = lane >> 4;
    const int fr = lane & 15;

    int rA, cqA, rB[2], cqB[2];
    {
        int p = wid * 1024 + lane * 16;
        int v = p >> 6;
        rA  = v ^ ((v >> 2) & 1);
        cqA = ((p >> 4) & 3) ^ (rA & 3);
    }
    #pragma unroll
    for (int t = 0; t < 2; ++t) {
        int p = (2 * wid + t) * 1024 + lane * 16;
        int v = p >> 6;
        int r = v ^ ((v >> 2) & 1);
        rB[t]  = r;
        cqB[t] = ((p >> 4) & 3) ^ (r & 3);
    }
    const short* pA  = A  + (size_t)(row0 + rA) * K + cqA * 8;
    const short* pB0 = Bm + (size_t)(col0 + rB[0]) * K + cqB[0] * 8;
    const short* pB1 = Bm + (size_t)(col0 + rB[1]) * K + cqB[1] * 8;
    const int aA  = wid * 1024;
    const int aB0 = 4096 + (2 * wid + 0) * 1024;
    const int aB1 = 4096 + (2 * wid + 1) * 1024;

    const int NS = K / 32;
    {
        char* lb = (char*)lds;
        GLD16(pA, lb + aA);
        GLD16(pB0, lb + aB0);
        GLD16(pB1, lb + aB1);
    }
    __syncthreads();

    for (int ks = 0; ks < NS; ++ks) {
        if (ks + 1 < NS) {
            const int kk = (ks + 1) * 32;
            char* lb = (char*)lds + ((ks + 1) & 1) * 12288;
            GLD16(pA + kk, lb + aA);
            GLD16(pB0 + kk, lb + aB0);
            GLD16(pB1 + kk, lb + aB1);
        }
        const short* lbc = lds + (ks & 1) * 6144;
        bf16x8 fa[2], fb[4];
        #pragma unroll
        for (int mf = 0; mf < 2; ++mf) {
            int r  = wm0 + mf * 16 + fr;
            int so = ((r * 64 + kq * 16) ^ ((r & 7) << 4)) >> 1;
            fa[mf] = *reinterpret_cast<const bf16x8*>(lbc + so);
        }
        #pragma unroll
        for (int nf = 0; nf < 4; ++nf) {
            int r  = wn0 + nf * 16 + fr;
            int so = ((r * 64 + kq * 16) ^ ((r & 7) << 4)) >> 1;
            fb[nf] = *reinterpret_cast<const bf16x8*>(lbc + 2048 + so);
        }
        __builtin_amdgcn_s_setprio(1);
        #pragma unroll
        for (int mf = 0; mf < 2; ++mf)
            #pragma unroll
            for (int nf = 0; nf < 4; ++nf)
                acc[mf][nf] = __builtin_amdgcn_mfma_f32_16x16x32_bf16(fa[mf], fb[nf], acc[mf][nf], 0, 0, 0);
        __builtin_amdgcn_s_setprio(0);
        __syncthreads();
    }

    const int rq = lane >> 4;
    #pragma unroll
    for (int nf = 0; nf < 4; ++nf) {
        int col = col0 + wn0 + nf * 16 + fr;
        if (col >= N) continue;
        float bia = bias[col];
        float g   = bn4[col];
        float be  = bn4[N + col];
        float mu  = bn4[2 * N + col];
        float va  = bn4[3 * N + col];
        float sc  = rsqrtf(va + EPS_) * g;
        #pragma unroll
        for (int mf = 0; mf < 2; ++mf) {
            #pragma unroll
            for (int r = 0; r < 4; ++r) {
                int row = row0 + wm0 + mf * 16 + rq * 4 + r;
                float v = acc[mf][nf][r] + bia;
                v = (v - mu) * sc + be;
                v = fmaxf(v, 0.f);
                if (ADD) v += bf2f((unsigned short)res[(size_t)row * N + col]);
                out[(size_t)row * N + col] = (short)f2bf(v);
            }
        }
    }
}

// ---------------- pooling + concat (+center direct from NHWC) -> bf16 feats ----------------
__global__ __launch_bounds__(256) void k_pool(const short* __restrict__ Hb,
                                              const short* __restrict__ nhwc,
                                              const int* __restrict__ cidx,
                                              short* __restrict__ feats) {
    int n = blockIdx.x;
    int b = n / NP_;
    const short* cen = nhwc + ((size_t)b * HW_ + cidx[n]) * C_;
    for (int c = threadIdx.x; c < C_; c += 256) {
        float s = 0.f, m = -INFINITY;
        #pragma unroll
        for (int j = 0; j < J_; j++) {
            float v = bf2f((unsigned short)Hb[((size_t)n * J_ + j) * C_ + c]);
            s += v;
            m = fmaxf(m, v);
        }
        feats[(size_t)n * 3 * C_ + c]          = (short)f2bf(s * (1.f / (float)J_));
        feats[(size_t)n * 3 * C_ + C_ + c]     = (short)f2bf(m);
        feats[(size_t)n * 3 * C_ + 2 * C_ + c] = cen[c];
    }
}

// ---------------- final projection (P bf16) ----------------
__global__ __launch_bounds__(256) void k_final(const short* __restrict__ P,
                                               const float* __restrict__ W2,
                                               const float* __restrict__ b2,
                                               float* __restrict__ out) {
    int g = blockIdx.x * 256 + threadIdx.x;
    if (g >= NSAMP * 2 * J_) return;
    int m = g / (2 * J_);
    int o = g % (2 * J_);
    const short* pr = P + (size_t)m * C_;
    const float* wr = W2 + (size_t)o * C_;
    float s = 0.f;
    for (int k = 0; k < C_; k += 4) {
        s = fmaf(bf2f((unsigned short)pr[k + 0]), wr[k + 0], s);
        s = fmaf(bf2f((unsigned short)pr[k + 1]), wr[k + 1], s);
        s = fmaf(bf2f((unsigned short)pr[k + 2]), wr[k + 2], s);
        s = fmaf(bf2f((unsigned short)pr[k + 3]), wr[k + 3], s);
    }
    out[g] = s + b2[o];
}

extern "C" void kernel_launch(void* const* d_in, const int* in_sizes, int n_in,
                              void* d_out, int out_size, void* d_ws, size_t ws_size,
                              hipStream_t stream) {
    const float* features = (const float*)d_in[0];
    const float* coords   = (const float*)d_in[1];
    const int*   center   = (const int*)d_in[2];
    const float* adj      = (const float*)d_in[3];
    const float* Wh       = (const float*)d_in[4];
    const float* bh       = (const float*)d_in[5];
    const float* bn_head  = (const float*)d_in[6];
    const float* Wres     = (const float*)d_in[7];
    const float* bres     = (const float*)d_in[8];
    const float* bn_res   = (const float*)d_in[9];
    const float* Wp1      = (const float*)d_in[10];
    const float* bp1      = (const float*)d_in[11];
    const float* bn_pred  = (const float*)d_in[12];
    const float* Wp2      = (const float*)d_in[13];
    const float* bp2      = (const float*)d_in[14];
    float* out = (float*)d_out;

    // ---- workspace layout (activation buffers padded +16 rows for 80-row staging) ----
    const size_t ACT = (size_t)(MROWS + 16) * C_ * 2;
    char* ws = (char*)d_ws;
    short* nhwc  = (short*)ws;   ws += (size_t)B_ * HW_ * C_ * 2;
    short* bufS  = (short*)ws;   ws += ACT;   // sampled X
    short* bufX  = (short*)ws;   ws += ACT;   // intra-layer temp
    short* bufH  = (short*)ws;   ws += ACT;   // running h
    short* featsB= (short*)ws;   ws += (size_t)NSAMP * 3 * C_ * 2;
    short* bufP  = (short*)ws;   ws += (size_t)NSAMP * C_ * 2;
    short* WtH   = (short*)ws;   ws += (size_t)NMAT * NPAD * C_ * 2;
    short* WpH   = (short*)ws;   ws += (size_t)NPAD * 3 * C_ * 2;

    dim3 gf(4, NSAMP / 4);            // fused conv GEMM: 1024 blocks (%8==0)
    dim3 gp(4, NSAMP / 64);           // pred GEMM: 64 blocks (%8==0)

    k_prep<<<NT_ + NW_, 256, 0, stream>>>(features, Wh, Wres, Wp1, nhwc, WtH, WpH);
    k_gather<<<NSAMP, 256, 0, stream>>>(nhwc, coords, bufS);

    // head: h = relu(bn(adj@(X@Wh)+bh))
    k_fgemm<false><<<gf, 256, 0, stream>>>(bufS, WtH, adj, bh, bn_head,
                                           nullptr, bufH, C_);

    for (int i = 0; i < L_; i++) {
        int m1 = 1 + 2 * i, m2 = 2 + 2 * i;
        k_fgemm<false><<<gf, 256, 0, stream>>>(
            bufH, WtH + (size_t)m1 * NPAD * C_, adj,
            bres + (size_t)(2 * i) * C_, bn_res + (size_t)(2 * i) * 4 * C_,
            nullptr, bufX, C_);
        k_fgemm<true><<<gf, 256, 0, stream>>>(
            bufX, WtH + (size_t)m2 * NPAD * C_, adj,
            bres + (size_t)(2 * i + 1) * C_, bn_res + (size_t)(2 * i + 1) * 4 * C_,
            bufH, bufH, C_);
    }

    k_pool<<<NSAMP, 256, 0, stream>>>(bufH, nhwc, center, featsB);

    // pred: relu(bn(feats @ Wp1^T + bp1)); M=1024, N=480, K=1440
    k_gemm_mfma<false><<<gp, 256, 0, stream>>>(featsB, WpH, bp1, bn_pred,
                                               nullptr, bufP, NSAMP, C_, 3 * C_);

    k_final<<<(NSAMP * 2 * J_ + 255) / 256, 256, 0, stream>>>(bufP, Wp2, bp2, out);
}

// Round 16
// 571.498 us; speedup vs baseline: 1.4493x; 1.4493x over previous
//
#include <hip/hip_runtime.h>
#include <math.h>

#define B_    16
#define NP_   64
#define J_    17
#define C_    480
#define H_    128
#define W_    128
#define L_    4
#define HW_   (H_ * W_)
#define NSAMP (B_ * NP_)      // 1024
#define MROWS (NSAMP * J_)    // 17408
#define EPS_  1e-5f
#define NMAT  (1 + 2 * L_)    // 9 graph-conv weight matrices
#define NPAD  512             // weight N padded to 512 rows (staging-safety margin)
#define TC    96              // transpose tile: channels
#define TS    64              // transpose tile: spatial
#define NT_   (256 * 5 * B_)  // 20480 transpose tiles
#define NW_   11520           // wsplit blocks

typedef __attribute__((ext_vector_type(8))) short bf16x8;
typedef __attribute__((ext_vector_type(4))) short bf16x4;
typedef __attribute__((ext_vector_type(4))) float f32x4;

__device__ __forceinline__ unsigned short f2bf(float f) {
    unsigned int u = __float_as_uint(f);
    unsigned int r = (u + 0x7fffu + ((u >> 16) & 1u)) >> 16;
    return (unsigned short)r;
}
__device__ __forceinline__ float bf2f(unsigned short h) {
    return __uint_as_float(((unsigned int)h) << 16);
}

// async global->LDS, 16B per lane; LDS dest = wave-uniform base + lane*16
#define GLD16(gsrc, ldst)                                                                 \
    __builtin_amdgcn_global_load_lds((const __attribute__((address_space(1))) void*)(gsrc), \
                                     (__attribute__((address_space(3))) void*)(ldst), 16, 0, 0)

// ---------------- merged prep: NCHW->NHWC bf16 transpose + weight split ----------------
__global__ __launch_bounds__(256) void k_prep(const float* __restrict__ feat,
                                              const float* __restrict__ Wh,
                                              const float* __restrict__ Wres,
                                              const float* __restrict__ Wp1,
                                              short* __restrict__ nhwc,
                                              short* __restrict__ WtH,
                                              short* __restrict__ WpH) {
    int bid = blockIdx.x;
    int tid = threadIdx.x;
    if (bid < NT_) {
        __shared__ float t[TC][73];   // stride 73 (mod 32 = 9): conflict-free
        int sb = bid & 255;
        int cb = (bid >> 8) % 5;
        int b  = bid / 1280;
        int c0 = cb * TC, s0 = sb * TS;
        const float* src = feat + ((size_t)b * C_ + c0) * HW_ + s0;
        #pragma unroll
        for (int i = 0; i < 6; ++i) {
            int f  = tid + i * 256;
            int c  = f >> 4;
            int sq = (f & 15) * 4;
            float4 v = *reinterpret_cast<const float4*>(src + (size_t)c * HW_ + sq);
            t[c][sq + 0] = v.x;
            t[c][sq + 1] = v.y;
            t[c][sq + 2] = v.z;
            t[c][sq + 3] = v.w;
        }
        __syncthreads();
        int sy = tid >> 2;
        int cx = (tid & 3) * (TC / 4);
        short* dst = nhwc + ((size_t)b * HW_ + s0 + sy) * C_ + c0 + cx;
        alignas(16) unsigned short tmp[TC / 4];
        #pragma unroll
        for (int i = 0; i < TC / 4; ++i) tmp[i] = f2bf(t[cx + i][sy]);
        #pragma unroll
        for (int i = 0; i < 3; ++i)
            *reinterpret_cast<uint4*>(dst + i * 8) = *reinterpret_cast<const uint4*>(tmp + i * 8);
    } else {
        int gid = (bid - NT_) * 256 + tid;
        const int t1 = NMAT * NPAD * C_;
        const int t2 = NPAD * 3 * C_;
        if (gid < t1) {
            int m   = gid / (NPAD * C_);
            int rem = gid % (NPAD * C_);
            int n = rem / C_;
            int k = rem % C_;
            float v = 0.f;
            if (n < C_) {
                const float* src = (m == 0) ? Wh : (Wres + (size_t)(m - 1) * C_ * C_);
                v = src[(size_t)k * C_ + n];
            }
            WtH[gid] = (short)f2bf(v);
        } else if (gid < t1 + t2) {
            int g2 = gid - t1;
            int n = g2 / (3 * C_);
            int k = g2 % (3 * C_);
            float v = (n < C_) ? Wp1[(size_t)n * 3 * C_ + k] : 0.f;
            WpH[g2] = (short)f2bf(v);
        }
    }
}

// ---------------- fused bilinear gather (NHWC bf16) + head adjacency mix -> bf16 A ----------------
__global__ __launch_bounds__(256) void k_gather_mix(const short* __restrict__ nhwc,
                                                    const float* __restrict__ coords,
                                                    const float* __restrict__ adj,
                                                    short* __restrict__ Ah) {
    __shared__ float sX[J_][C_];
    __shared__ float sadj[J_ * J_];
    __shared__ float sw[J_][4];
    __shared__ int   si[J_];
    int n = blockIdx.x;
    int b = n / NP_;
    for (int t = threadIdx.x; t < J_ * J_; t += 256) sadj[t] = adj[t];
    if (threadIdx.x < J_) {
        int j = threadIdx.x;
        int p = n * J_ + j;
        float x = coords[p * 2 + 0];
        float y = coords[p * 2 + 1];
        float x0f = fminf(fmaxf(floorf(x), 0.f), (float)(W_ - 2));
        float y0f = fminf(fmaxf(floorf(y), 0.f), (float)(H_ - 2));
        float wx = x - x0f, wy = y - y0f;
        sw[j][0] = (1.f - wx) * (1.f - wy);
        sw[j][1] = wx * (1.f - wy);
        sw[j][2] = (1.f - wx) * wy;
        sw[j][3] = wx * wy;
        si[j] = (int)y0f * W_ + (int)x0f;
    }
    __syncthreads();
    const short* base = nhwc + (size_t)b * HW_ * C_;
    for (int idx = threadIdx.x; idx < J_ * (C_ / 8); idx += 256) {
        int j  = idx / (C_ / 8);
        int c8 = (idx - j * (C_ / 8)) * 8;
        const short* p00 = base + (size_t)si[j] * C_ + c8;
        bf16x8 v00 = *reinterpret_cast<const bf16x8*>(p00);
        bf16x8 v01 = *reinterpret_cast<const bf16x8*>(p00 + C_);
        bf16x8 v10 = *reinterpret_cast<const bf16x8*>(p00 + W_ * C_);
        bf16x8 v11 = *reinterpret_cast<const bf16x8*>(p00 + W_ * C_ + C_);
        float w0 = sw[j][0], w1 = sw[j][1], w2 = sw[j][2], w3 = sw[j][3];
        #pragma unroll
        for (int e = 0; e < 8; ++e) {
            sX[j][c8 + e] = bf2f((unsigned short)v00[e]) * w0 +
                            bf2f((unsigned short)v01[e]) * w1 +
                            bf2f((unsigned short)v10[e]) * w2 +
                            bf2f((unsigned short)v11[e]) * w3;
        }
    }
    __syncthreads();
    size_t obase = (size_t)n * J_ * C_;
    for (int c = threadIdx.x; c < C_; c += 256) {
        float xv[J_];
        #pragma unroll
        for (int k = 0; k < J_; k++) xv[k] = sX[k][c];
        #pragma unroll
        for (int j = 0; j < J_; j++) {
            float s = 0.f;
            #pragma unroll
            for (int k = 0; k < J_; k++) s += sadj[j * J_ + k] * xv[k];
            Ah[obase + (size_t)j * C_ + c] = (short)f2bf(s);
        }
    }
}

// ---------------- adjacency mix on bf16 ----------------
__global__ __launch_bounds__(256) void k_mix_bf16(const short* __restrict__ Xin,
                                                  const float* __restrict__ adj,
                                                  short* __restrict__ Ah) {
    __shared__ float sadj[J_ * J_];
    for (int t = threadIdx.x; t < J_ * J_; t += 256) sadj[t] = adj[t];
    __syncthreads();
    int t = threadIdx.x;
    if (t >= 240) return;
    int n  = blockIdx.x * 2 + (t / 120);
    int c4 = (t % 120) * 4;
    const short* xb = Xin + (size_t)n * J_ * C_ + c4;
    float xf[J_][4];
    #pragma unroll
    for (int k = 0; k < J_; k++) {
        bf16x4 v = *reinterpret_cast<const bf16x4*>(xb + (size_t)k * C_);
        #pragma unroll
        for (int e = 0; e < 4; ++e) xf[k][e] = bf2f((unsigned short)v[e]);
    }
    short* yb = Ah + (size_t)n * J_ * C_ + c4;
    #pragma unroll
    for (int j = 0; j < J_; j++) {
        float a0 = 0.f, a1 = 0.f, a2 = 0.f, a3 = 0.f;
        #pragma unroll
        for (int k = 0; k < J_; k++) {
            float w = sadj[j * J_ + k];
            a0 = fmaf(w, xf[k][0], a0);
            a1 = fmaf(w, xf[k][1], a1);
            a2 = fmaf(w, xf[k][2], a2);
            a3 = fmaf(w, xf[k][3], a3);
        }
        bf16x4 o = {(short)f2bf(a0), (short)f2bf(a1), (short)f2bf(a2), (short)f2bf(a3)};
        *reinterpret_cast<bf16x4*>(yb + (size_t)j * C_) = o;
    }
}

// ---------------- 1-term bf16 MFMA GEMM: BM=64 x BN=96 (exact-fit, no col mask) ----------------
// out[m,n](bf16) = relu(bn(sum_k A[m,k]B[k,n] + bias[n])) (+ res bf16)
// Tile 64x96, 4 waves as 2(m)x2(n); wave = 32x48 out (2x3 16x16x32 frags, acc 24 VGPR).
// LDS per buffer: A 4KB (slices 0-3) + B 6KB (slices 4-9) = 10KB; double buffer 20KB.
// Wave w stages A slice w, B slice 4+w, and (w<2) B slice 8+w. XOR swizzle
// byte p=(r*64+cq*16)^((r&7)<<4): linear gload_lds dest + inverse-swizzled source.
// N must equal gridDim.x*96 (exact); K % 32 == 0.
template <bool ADD>
__global__ __launch_bounds__(256) void k_gemm_mfma(const short* __restrict__ A,
                                                   const short* __restrict__ Bm,
                                                   const float* __restrict__ bias,
                                                   const float* __restrict__ bn4,
                                                   const short* res,   // may alias out
                                                   short* out,
                                                   int M, int N, int K) {
    __shared__ short lds[2 * 5120];   // [buf][A(2048) | B(3072)] shorts, 20 KB

    int nwg = gridDim.x * gridDim.y;
    int lin = blockIdx.y * gridDim.x + blockIdx.x;
    int cpx = nwg >> 3;               // caller guarantees nwg % 8 == 0
    int swz = (lin & 7) * cpx + (lin >> 3);
    const int row0 = (swz / gridDim.x) * 64;
    const int col0 = (swz % gridDim.x) * 96;

    const int tid  = threadIdx.x;
    const int lane = tid & 63;
    const int wid  = tid >> 6;
    const int wm0  = (wid >> 1) * 32;    // wave m-offset (0/32)
    const int wn0  = (wid & 1) * 48;     // wave n-offset (0/48)

    f32x4 acc[2][3];
    #pragma unroll
    for (int i = 0; i < 2; i++)
        #pragma unroll
        for (int j = 0; j < 3; j++) acc[i][j] = (f32x4){0.f, 0.f, 0.f, 0.f};

    const int kq = lane >> 4;
    const int fr = lane & 15;

    // staging slices: 0-3 = A rows sl*16.. ; 4-9 = B rows (sl-4)*16..
    // wave w: slices {w, 4+w, 8+w(if w<2)}
    const short* psrc[3];
    int lof[3];
    #pragma unroll
    for (int t = 0; t < 3; ++t) {
        int sl = (t == 0) ? wid : (t == 1 ? 4 + wid : 8 + wid);
        if (sl > 9) sl = 9;              // waves 2,3 have no 3rd slice (load guarded off)
        int isA  = (sl < 4);
        int prel = (isA ? sl : sl - 4) * 1024 + lane * 16;
        int v = prel >> 6;
        int r = v ^ ((v >> 2) & 1);
        int cq = ((prel >> 4) & 3) ^ (r & 3);
        psrc[t] = isA ? (A + (size_t)(row0 + r) * K + cq * 8)
                      : (Bm + (size_t)(col0 + r) * K + cq * 8);
        lof[t] = sl * 1024;
    }
    const bool has3 = (wid < 2);

    const int NS = K / 32;
    {   // prologue: stage tile 0 into buf 0
        char* lb = (char*)lds;
        GLD16(psrc[0], lb + lof[0]);
        GLD16(psrc[1], lb + lof[1]);
        if (has3) GLD16(psrc[2], lb + lof[2]);
    }
    __syncthreads();

    for (int ks = 0; ks < NS; ++ks) {
        if (ks + 1 < NS) {            // prefetch next tile into other buffer
            const int kk = (ks + 1) * 32;
            char* lb = (char*)lds + ((ks + 1) & 1) * 10240;
            GLD16(psrc[0] + kk, lb + lof[0]);
            GLD16(psrc[1] + kk, lb + lof[1]);
            if (has3) GLD16(psrc[2] + kk, lb + lof[2]);
        }
        const short* lbc = lds + (ks & 1) * 5120;
        bf16x8 fa[2], fb[3];
        #pragma unroll
        for (int mf = 0; mf < 2; ++mf) {
            int r  = wm0 + mf * 16 + fr;
            int so = ((r * 64 + kq * 16) ^ ((r & 7) << 4)) >> 1;
            fa[mf] = *reinterpret_cast<const bf16x8*>(lbc + so);
        }
        #pragma unroll
        for (int nf = 0; nf < 3; ++nf) {
            int r  = wn0 + nf * 16 + fr;
            int so = ((r * 64 + kq * 16) ^ ((r & 7) << 4)) >> 1;
            fb[nf] = *reinterpret_cast<const bf16x8*>(lbc + 2048 + so);
        }
        __builtin_amdgcn_s_setprio(1);
        #pragma unroll
        for (int mf = 0; mf < 2; ++mf)
            #pragma unroll
            for (int nf = 0; nf < 3; ++nf)
                acc[mf][nf] = __builtin_amdgcn_mfma_f32_16x16x32_bf16(fa[mf], fb[nf], acc[mf][nf], 0, 0, 0);
        __builtin_amdgcn_s_setprio(0);
        __syncthreads();   // drains prefetch + guards buffer reuse
    }

    // ---- epilogue: C/D layout col=lane&15, row=(lane>>4)*4+reg; all cols in-bounds ----
    const int rq = lane >> 4;
    #pragma unroll
    for (int nf = 0; nf < 3; ++nf) {
        int col = col0 + wn0 + nf * 16 + fr;
        float bia = bias[col];
        float g   = bn4[col];
        float be  = bn4[N + col];
        float mu  = bn4[2 * N + col];
        float va  = bn4[3 * N + col];
        float sc  = rsqrtf(va + EPS_) * g;
        #pragma unroll
        for (int mf = 0; mf < 2; ++mf) {
            #pragma unroll
            for (int r = 0; r < 4; ++r) {
                int row = row0 + wm0 + mf * 16 + rq * 4 + r;
                float v = acc[mf][nf][r] + bia;
                v = (v - mu) * sc + be;
                v = fmaxf(v, 0.f);
                if (ADD) v += bf2f((unsigned short)res[(size_t)row * N + col]);
                out[(size_t)row * N + col] = (short)f2bf(v);
            }
        }
    }
}

// ---------------- pooling + concat (+center direct from NHWC) -> bf16 feats ----------------
__global__ __launch_bounds__(256) void k_pool(const short* __restrict__ Hb,
                                              const short* __restrict__ nhwc,
                                              const int* __restrict__ cidx,
                                              short* __restrict__ feats) {
    int n = blockIdx.x;
    int b = n / NP_;
    const short* cen = nhwc + ((size_t)b * HW_ + cidx[n]) * C_;
    for (int c = threadIdx.x; c < C_; c += 256) {
        float s = 0.f, m = -INFINITY;
        #pragma unroll
        for (int j = 0; j < J_; j++) {
            float v = bf2f((unsigned short)Hb[((size_t)n * J_ + j) * C_ + c]);
            s += v;
            m = fmaxf(m, v);
        }
        feats[(size_t)n * 3 * C_ + c]          = (short)f2bf(s * (1.f / (float)J_));
        feats[(size_t)n * 3 * C_ + C_ + c]     = (short)f2bf(m);
        feats[(size_t)n * 3 * C_ + 2 * C_ + c] = cen[c];
    }
}

// ---------------- final projection (P bf16) ----------------
__global__ __launch_bounds__(256) void k_final(const short* __restrict__ P,
                                               const float* __restrict__ W2,
                                               const float* __restrict__ b2,
                                               float* __restrict__ out) {
    int g = blockIdx.x * 256 + threadIdx.x;
    if (g >= NSAMP * 2 * J_) return;
    int m = g / (2 * J_);
    int o = g % (2 * J_);
    const short* pr = P + (size_t)m * C_;
    const float* wr = W2 + (size_t)o * C_;
    float s = 0.f;
    for (int k = 0; k < C_; k += 4) {
        s = fmaf(bf2f((unsigned short)pr[k + 0]), wr[k + 0], s);
        s = fmaf(bf2f((unsigned short)pr[k + 1]), wr[k + 1], s);
        s = fmaf(bf2f((unsigned short)pr[k + 2]), wr[k + 2], s);
        s = fmaf(bf2f((unsigned short)pr[k + 3]), wr[k + 3], s);
    }
    out[g] = s + b2[o];
}

extern "C" void kernel_launch(void* const* d_in, const int* in_sizes, int n_in,
                              void* d_out, int out_size, void* d_ws, size_t ws_size,
                              hipStream_t stream) {
    const float* features = (const float*)d_in[0];
    const float* coords   = (const float*)d_in[1];
    const int*   center   = (const int*)d_in[2];
    const float* adj      = (const float*)d_in[3];
    const float* Wh       = (const float*)d_in[4];
    const float* bh       = (const float*)d_in[5];
    const float* bn_head  = (const float*)d_in[6];
    const float* Wres     = (const float*)d_in[7];
    const float* bres     = (const float*)d_in[8];
    const float* bn_res   = (const float*)d_in[9];
    const float* Wp1      = (const float*)d_in[10];
    const float* bp1      = (const float*)d_in[11];
    const float* bn_pred  = (const float*)d_in[12];
    const float* Wp2      = (const float*)d_in[13];
    const float* bp2      = (const float*)d_in[14];
    float* out = (float*)d_out;

    // ---- workspace layout ----
    char* ws = (char*)d_ws;
    short* nhwc  = (short*)ws;   ws += (size_t)B_ * HW_ * C_ * 2;
    short* bufX  = (short*)ws;   ws += (size_t)MROWS * C_ * 2;
    short* bufH  = (short*)ws;   ws += (size_t)MROWS * C_ * 2;
    short* AhB   = (short*)ws;   ws += (size_t)MROWS * C_ * 2;
    short* featsB= (short*)ws;   ws += (size_t)NSAMP * 3 * C_ * 2;
    short* bufP  = (short*)ws;   ws += (size_t)NSAMP * C_ * 2;
    short* WtH   = (short*)ws;   ws += (size_t)NMAT * NPAD * C_ * 2;
    short* WpH   = (short*)ws;   ws += (size_t)NPAD * 3 * C_ * 2;

    dim3 gg(5, MROWS / 64);           // 1360 blocks (1360 % 8 == 0), cols 5x96 = 480 exact
    dim3 gp(5, NSAMP / 64);           // 80 blocks   (80 % 8 == 0)

    k_prep<<<NT_ + NW_, 256, 0, stream>>>(features, Wh, Wres, Wp1, nhwc, WtH, WpH);

    k_gather_mix<<<NSAMP, 256, 0, stream>>>(nhwc, coords, adj, AhB);
    k_gemm_mfma<false><<<gg, 256, 0, stream>>>(AhB, WtH, bh, bn_head,
                                               nullptr, bufH, MROWS, C_, C_);

    for (int i = 0; i < L_; i++) {
        int m1 = 1 + 2 * i, m2 = 2 + 2 * i;
        k_mix_bf16<<<NSAMP / 2, 256, 0, stream>>>(bufH, adj, AhB);
        k_gemm_mfma<false><<<gg, 256, 0, stream>>>(
            AhB, WtH + (size_t)m1 * NPAD * C_,
            bres + (size_t)(2 * i) * C_, bn_res + (size_t)(2 * i) * 4 * C_,
            nullptr, bufX, MROWS, C_, C_);
        k_mix_bf16<<<NSAMP / 2, 256, 0, stream>>>(bufX, adj, AhB);
        k_gemm_mfma<true><<<gg, 256, 0, stream>>>(
            AhB, WtH + (size_t)m2 * NPAD * C_,
            bres + (size_t)(2 * i + 1) * C_, bn_res + (size_t)(2 * i + 1) * 4 * C_,
            bufH, bufH, MROWS, C_, C_);
    }

    k_pool<<<NSAMP, 256, 0, stream>>>(bufH, nhwc, center, featsB);

    // pred: relu(bn(feats @ Wp1^T + bp1)); M=1024, N=480, K=1440
    k_gemm_mfma<false><<<gp, 256, 0, stream>>>(featsB, WpH, bp1, bn_pred,
                                               nullptr, bufP, NSAMP, C_, 3 * C_);

    k_final<<<(NSAMP * 2 * J_ + 255) / 256, 256, 0, stream>>>(bufP, Wp2, bp2, out);
}

// Round 17
// 566.960 us; speedup vs baseline: 1.4609x; 1.0080x over previous
//
#include <hip/hip_runtime.h>
#include <math.h>

#define B_    16
#define NP_   64
#define J_    17
#define C_    480
#define H_    128
#define W_    128
#define L_    4
#define HW_   (H_ * W_)
#define NSAMP (B_ * NP_)      // 1024
#define MROWS (NSAMP * J_)    // 17408
#define EPS_  1e-5f
#define NMAT  (1 + 2 * L_)    // 9 graph-conv weight matrices
#define NPAD  512             // weight N padded to 512 rows (staging-safety margin)
#define TC    96              // transpose tile: channels
#define TS    64              // transpose tile: spatial
#define NT_   (256 * 5 * B_)  // 20480 transpose tiles
#define NW_   11520           // wsplit blocks
#define PADT  65              // f32 LDS stride: 65 % 32 == 1 -> exactly 2-way (free)

typedef __attribute__((ext_vector_type(8))) short bf16x8;
typedef __attribute__((ext_vector_type(4))) short bf16x4;
typedef __attribute__((ext_vector_type(4))) float f32x4;

__device__ __forceinline__ unsigned short f2bf(float f) {
    unsigned int u = __float_as_uint(f);
    unsigned int r = (u + 0x7fffu + ((u >> 16) & 1u)) >> 16;
    return (unsigned short)r;
}
__device__ __forceinline__ float bf2f(unsigned short h) {
    return __uint_as_float(((unsigned int)h) << 16);
}

// async global->LDS, 16B per lane; LDS dest = wave-uniform base + lane*16
#define GLD16(gsrc, ldst)                                                                 \
    __builtin_amdgcn_global_load_lds((const __attribute__((address_space(1))) void*)(gsrc), \
                                     (__attribute__((address_space(3))) void*)(ldst), 16, 0, 0)

// ---------------- merged prep: NCHW->NHWC bf16 transpose + weight split ----------------
// features reads are NONTEMPORAL (read-once streaming; keeps nhwc L3-resident for gather/pool).
__global__ __launch_bounds__(256) void k_prep(const float* __restrict__ feat,
                                              const float* __restrict__ Wh,
                                              const float* __restrict__ Wres,
                                              const float* __restrict__ Wp1,
                                              short* __restrict__ nhwc,
                                              short* __restrict__ WtH,
                                              short* __restrict__ WpH) {
    int bid = blockIdx.x;
    int tid = threadIdx.x;
    if (bid < NT_) {
        __shared__ float t[TC][PADT];   // 96 x 65 f32 = 24.96 KB -> 6 blocks/CU
        int sb = bid & 255;
        int cb = (bid >> 8) % 5;
        int b  = bid / 1280;
        int c0 = cb * TC, s0 = sb * TS;
        const float* src = feat + ((size_t)b * C_ + c0) * HW_ + s0;
        #pragma unroll
        for (int i = 0; i < 6; ++i) {
            int f  = tid + i * 256;
            int c  = f >> 4;
            int sq = (f & 15) * 4;
            f32x4 v = __builtin_nontemporal_load(
                reinterpret_cast<const f32x4*>(src + (size_t)c * HW_ + sq));
            t[c][sq + 0] = v[0];
            t[c][sq + 1] = v[1];
            t[c][sq + 2] = v[2];
            t[c][sq + 3] = v[3];
        }
        __syncthreads();
        int sy = tid >> 2;
        int cx = (tid & 3) * (TC / 4);
        short* dst = nhwc + ((size_t)b * HW_ + s0 + sy) * C_ + c0 + cx;
        alignas(16) unsigned short tmp[TC / 4];
        #pragma unroll
        for (int i = 0; i < TC / 4; ++i) tmp[i] = f2bf(t[cx + i][sy]);
        #pragma unroll
        for (int i = 0; i < 3; ++i)
            *reinterpret_cast<uint4*>(dst + i * 8) = *reinterpret_cast<const uint4*>(tmp + i * 8);
    } else {
        int gid = (bid - NT_) * 256 + tid;
        const int t1 = NMAT * NPAD * C_;
        const int t2 = NPAD * 3 * C_;
        if (gid < t1) {
            int m   = gid / (NPAD * C_);
            int rem = gid % (NPAD * C_);
            int n = rem / C_;
            int k = rem % C_;
            float v = 0.f;
            if (n < C_) {
                const float* src = (m == 0) ? Wh : (Wres + (size_t)(m - 1) * C_ * C_);
                v = __builtin_nontemporal_load(&src[(size_t)k * C_ + n]);
            }
            WtH[gid] = (short)f2bf(v);
        } else if (gid < t1 + t2) {
            int g2 = gid - t1;
            int n = g2 / (3 * C_);
            int k = g2 % (3 * C_);
            float v = (n < C_) ? __builtin_nontemporal_load(&Wp1[(size_t)n * 3 * C_ + k]) : 0.f;
            WpH[g2] = (short)f2bf(v);
        }
    }
}

// ---------------- fused bilinear gather (NHWC bf16) + head adjacency mix -> bf16 A ----------------
__global__ __launch_bounds__(256) void k_gather_mix(const short* __restrict__ nhwc,
                                                    const float* __restrict__ coords,
                                                    const float* __restrict__ adj,
                                                    short* __restrict__ Ah) {
    __shared__ float sX[J_][C_];
    __shared__ float sadj[J_ * J_];
    __shared__ float sw[J_][4];
    __shared__ int   si[J_];
    int n = blockIdx.x;
    int b = n / NP_;
    for (int t = threadIdx.x; t < J_ * J_; t += 256) sadj[t] = adj[t];
    if (threadIdx.x < J_) {
        int j = threadIdx.x;
        int p = n * J_ + j;
        float x = coords[p * 2 + 0];
        float y = coords[p * 2 + 1];
        float x0f = fminf(fmaxf(floorf(x), 0.f), (float)(W_ - 2));
        float y0f = fminf(fmaxf(floorf(y), 0.f), (float)(H_ - 2));
        float wx = x - x0f, wy = y - y0f;
        sw[j][0] = (1.f - wx) * (1.f - wy);
        sw[j][1] = wx * (1.f - wy);
        sw[j][2] = (1.f - wx) * wy;
        sw[j][3] = wx * wy;
        si[j] = (int)y0f * W_ + (int)x0f;
    }
    __syncthreads();
    const short* base = nhwc + (size_t)b * HW_ * C_;
    for (int idx = threadIdx.x; idx < J_ * (C_ / 8); idx += 256) {
        int j  = idx / (C_ / 8);
        int c8 = (idx - j * (C_ / 8)) * 8;
        const short* p00 = base + (size_t)si[j] * C_ + c8;
        bf16x8 v00 = *reinterpret_cast<const bf16x8*>(p00);
        bf16x8 v01 = *reinterpret_cast<const bf16x8*>(p00 + C_);
        bf16x8 v10 = *reinterpret_cast<const bf16x8*>(p00 + W_ * C_);
        bf16x8 v11 = *reinterpret_cast<const bf16x8*>(p00 + W_ * C_ + C_);
        float w0 = sw[j][0], w1 = sw[j][1], w2 = sw[j][2], w3 = sw[j][3];
        #pragma unroll
        for (int e = 0; e < 8; ++e) {
            sX[j][c8 + e] = bf2f((unsigned short)v00[e]) * w0 +
                            bf2f((unsigned short)v01[e]) * w1 +
                            bf2f((unsigned short)v10[e]) * w2 +
                            bf2f((unsigned short)v11[e]) * w3;
        }
    }
    __syncthreads();
    size_t obase = (size_t)n * J_ * C_;
    for (int c = threadIdx.x; c < C_; c += 256) {
        float xv[J_];
        #pragma unroll
        for (int k = 0; k < J_; k++) xv[k] = sX[k][c];
        #pragma unroll
        for (int j = 0; j < J_; j++) {
            float s = 0.f;
            #pragma unroll
            for (int k = 0; k < J_; k++) s += sadj[j * J_ + k] * xv[k];
            Ah[obase + (size_t)j * C_ + c] = (short)f2bf(s);
        }
    }
}

// ---------------- adjacency mix on bf16 ----------------
__global__ __launch_bounds__(256) void k_mix_bf16(const short* __restrict__ Xin,
                                                  const float* __restrict__ adj,
                                                  short* __restrict__ Ah) {
    __shared__ float sadj[J_ * J_];
    for (int t = threadIdx.x; t < J_ * J_; t += 256) sadj[t] = adj[t];
    __syncthreads();
    int t = threadIdx.x;
    if (t >= 240) return;
    int n  = blockIdx.x * 2 + (t / 120);
    int c4 = (t % 120) * 4;
    const short* xb = Xin + (size_t)n * J_ * C_ + c4;
    float xf[J_][4];
    #pragma unroll
    for (int k = 0; k < J_; k++) {
        bf16x4 v = *reinterpret_cast<const bf16x4*>(xb + (size_t)k * C_);
        #pragma unroll
        for (int e = 0; e < 4; ++e) xf[k][e] = bf2f((unsigned short)v[e]);
    }
    short* yb = Ah + (size_t)n * J_ * C_ + c4;
    #pragma unroll
    for (int j = 0; j < J_; j++) {
        float a0 = 0.f, a1 = 0.f, a2 = 0.f, a3 = 0.f;
        #pragma unroll
        for (int k = 0; k < J_; k++) {
            float w = sadj[j * J_ + k];
            a0 = fmaf(w, xf[k][0], a0);
            a1 = fmaf(w, xf[k][1], a1);
            a2 = fmaf(w, xf[k][2], a2);
            a3 = fmaf(w, xf[k][3], a3);
        }
        bf16x4 o = {(short)f2bf(a0), (short)f2bf(a1), (short)f2bf(a2), (short)f2bf(a3)};
        *reinterpret_cast<bf16x4*>(yb + (size_t)j * C_) = o;
    }
}

// ---------------- 1-term bf16 MFMA GEMM: BM=64 x BN=96 (exact-fit, no col mask) ----------------
template <bool ADD>
__global__ __launch_bounds__(256) void k_gemm_mfma(const short* __restrict__ A,
                                                   const short* __restrict__ Bm,
                                                   const float* __restrict__ bias,
                                                   const float* __restrict__ bn4,
                                                   const short* res,   // may alias out
                                                   short* out,
                                                   int M, int N, int K) {
    __shared__ short lds[2 * 5120];   // [buf][A(2048) | B(3072)] shorts, 20 KB

    int nwg = gridDim.x * gridDim.y;
    int lin = blockIdx.y * gridDim.x + blockIdx.x;
    int cpx = nwg >> 3;               // caller guarantees nwg % 8 == 0
    int swz = (lin & 7) * cpx + (lin >> 3);
    const int row0 = (swz / gridDim.x) * 64;
    const int col0 = (swz % gridDim.x) * 96;

    const int tid  = threadIdx.x;
    const int lane = tid & 63;
    const int wid  = tid >> 6;
    const int wm0  = (wid >> 1) * 32;
    const int wn0  = (wid & 1) * 48;

    f32x4 acc[2][3];
    #pragma unroll
    for (int i = 0; i < 2; i++)
        #pragma unroll
        for (int j = 0; j < 3; j++) acc[i][j] = (f32x4){0.f, 0.f, 0.f, 0.f};

    const int kq = lane >> 4;
    const int fr = lane & 15;

    const short* psrc[3];
    int lof[3];
    #pragma unroll
    for (int t = 0; t < 3; ++t) {
        int sl = (t == 0) ? wid : (t == 1 ? 4 + wid : 8 + wid);
        if (sl > 9) sl = 9;
        int isA  = (sl < 4);
        int prel = (isA ? sl : sl - 4) * 1024 + lane * 16;
        int v = prel >> 6;
        int r = v ^ ((v >> 2) & 1);
        int cq = ((prel >> 4) & 3) ^ (r & 3);
        psrc[t] = isA ? (A + (size_t)(row0 + r) * K + cq * 8)
                      : (Bm + (size_t)(col0 + r) * K + cq * 8);
        lof[t] = sl * 1024;
    }
    const bool has3 = (wid < 2);

    const int NS = K / 32;
    {
        char* lb = (char*)lds;
        GLD16(psrc[0], lb + lof[0]);
        GLD16(psrc[1], lb + lof[1]);
        if (has3) GLD16(psrc[2], lb + lof[2]);
    }
    __syncthreads();

    for (int ks = 0; ks < NS; ++ks) {
        if (ks + 1 < NS) {
            const int kk = (ks + 1) * 32;
            char* lb = (char*)lds + ((ks + 1) & 1) * 10240;
            GLD16(psrc[0] + kk, lb + lof[0]);
            GLD16(psrc[1] + kk, lb + lof[1]);
            if (has3) GLD16(psrc[2] + kk, lb + lof[2]);
        }
        const short* lbc = lds + (ks & 1) * 5120;
        bf16x8 fa[2], fb[3];
        #pragma unroll
        for (int mf = 0; mf < 2; ++mf) {
            int r  = wm0 + mf * 16 + fr;
            int so = ((r * 64 + kq * 16) ^ ((r & 7) << 4)) >> 1;
            fa[mf] = *reinterpret_cast<const bf16x8*>(lbc + so);
        }
        #pragma unroll
        for (int nf = 0; nf < 3; ++nf) {
            int r  = wn0 + nf * 16 + fr;
            int so = ((r * 64 + kq * 16) ^ ((r & 7) << 4)) >> 1;
            fb[nf] = *reinterpret_cast<const bf16x8*>(lbc + 2048 + so);
        }
        __builtin_amdgcn_s_setprio(1);
        #pragma unroll
        for (int mf = 0; mf < 2; ++mf)
            #pragma unroll
            for (int nf = 0; nf < 3; ++nf)
                acc[mf][nf] = __builtin_amdgcn_mfma_f32_16x16x32_bf16(fa[mf], fb[nf], acc[mf][nf], 0, 0, 0);
        __builtin_amdgcn_s_setprio(0);
        __syncthreads();
    }

    const int rq = lane >> 4;
    #pragma unroll
    for (int nf = 0; nf < 3; ++nf) {
        int col = col0 + wn0 + nf * 16 + fr;
        float bia = bias[col];
        float g   = bn4[col];
        float be  = bn4[N + col];
        float mu  = bn4[2 * N + col];
        float va  = bn4[3 * N + col];
        float sc  = rsqrtf(va + EPS_) * g;
        #pragma unroll
        for (int mf = 0; mf < 2; ++mf) {
            #pragma unroll
            for (int r = 0; r < 4; ++r) {
                int row = row0 + wm0 + mf * 16 + rq * 4 + r;
                float v = acc[mf][nf][r] + bia;
                v = (v - mu) * sc + be;
                v = fmaxf(v, 0.f);
                if (ADD) v += bf2f((unsigned short)res[(size_t)row * N + col]);
                out[(size_t)row * N + col] = (short)f2bf(v);
            }
        }
    }
}

// ---------------- pooling + concat (+center direct from NHWC) -> bf16 feats ----------------
__global__ __launch_bounds__(256) void k_pool(const short* __restrict__ Hb,
                                              const short* __restrict__ nhwc,
                                              const int* __restrict__ cidx,
                                              short* __restrict__ feats) {
    int n = blockIdx.x;
    int b = n / NP_;
    const short* cen = nhwc + ((size_t)b * HW_ + cidx[n]) * C_;
    for (int c = threadIdx.x; c < C_; c += 256) {
        float s = 0.f, m = -INFINITY;
        #pragma unroll
        for (int j = 0; j < J_; j++) {
            float v = bf2f((unsigned short)Hb[((size_t)n * J_ + j) * C_ + c]);
            s += v;
            m = fmaxf(m, v);
        }
        feats[(size_t)n * 3 * C_ + c]          = (short)f2bf(s * (1.f / (float)J_));
        feats[(size_t)n * 3 * C_ + C_ + c]     = (short)f2bf(m);
        feats[(size_t)n * 3 * C_ + 2 * C_ + c] = cen[c];
    }
}

// ---------------- final projection (P bf16) ----------------
__global__ __launch_bounds__(256) void k_final(const short* __restrict__ P,
                                               const float* __restrict__ W2,
                                               const float* __restrict__ b2,
                                               float* __restrict__ out) {
    int g = blockIdx.x * 256 + threadIdx.x;
    if (g >= NSAMP * 2 * J_) return;
    int m = g / (2 * J_);
    int o = g % (2 * J_);
    const short* pr = P + (size_t)m * C_;
    const float* wr = W2 + (size_t)o * C_;
    float s = 0.f;
    for (int k = 0; k < C_; k += 4) {
        s = fmaf(bf2f((unsigned short)pr[k + 0]), wr[k + 0], s);
        s = fmaf(bf2f((unsigned short)pr[k + 1]), wr[k + 1], s);
        s = fmaf(bf2f((unsigned short)pr[k + 2]), wr[k + 2], s);
        s = fmaf(bf2f((unsigned short)pr[k + 3]), wr[k + 3], s);
    }
    out[g] = s + b2[o];
}

extern "C" void kernel_launch(void* const* d_in, const int* in_sizes, int n_in,
                              void* d_out, int out_size, void* d_ws, size_t ws_size,
                              hipStream_t stream) {
    const float* features = (const float*)d_in[0];
    const float* coords   = (const float*)d_in[1];
    const int*   center   = (const int*)d_in[2];
    const float* adj      = (const float*)d_in[3];
    const float* Wh       = (const float*)d_in[4];
    const float* bh       = (const float*)d_in[5];
    const float* bn_head  = (const float*)d_in[6];
    const float* Wres     = (const float*)d_in[7];
    const float* bres     = (const float*)d_in[8];
    const float* bn_res   = (const float*)d_in[9];
    const float* Wp1      = (const float*)d_in[10];
    const float* bp1      = (const float*)d_in[11];
    const float* bn_pred  = (const float*)d_in[12];
    const float* Wp2      = (const float*)d_in[13];
    const float* bp2      = (const float*)d_in[14];
    float* out = (float*)d_out;

    // ---- workspace layout ----
    char* ws = (char*)d_ws;
    short* nhwc  = (short*)ws;   ws += (size_t)B_ * HW_ * C_ * 2;
    short* bufX  = (short*)ws;   ws += (size_t)MROWS * C_ * 2;
    short* bufH  = (short*)ws;   ws += (size_t)MROWS * C_ * 2;
    short* AhB   = (short*)ws;   ws += (size_t)MROWS * C_ * 2;
    short* featsB= (short*)ws;   ws += (size_t)NSAMP * 3 * C_ * 2;
    short* bufP  = (short*)ws;   ws += (size_t)NSAMP * C_ * 2;
    short* WtH   = (short*)ws;   ws += (size_t)NMAT * NPAD * C_ * 2;
    short* WpH   = (short*)ws;   ws += (size_t)NPAD * 3 * C_ * 2;

    dim3 gg(5, MROWS / 64);           // 1360 blocks (1360 % 8 == 0), cols 5x96 = 480 exact
    dim3 gp(5, NSAMP / 64);           // 80 blocks   (80 % 8 == 0)

    k_prep<<<NT_ + NW_, 256, 0, stream>>>(features, Wh, Wres, Wp1, nhwc, WtH, WpH);

    k_gather_mix<<<NSAMP, 256, 0, stream>>>(nhwc, coords, adj, AhB);
    k_gemm_mfma<false><<<gg, 256, 0, stream>>>(AhB, WtH, bh, bn_head,
                                               nullptr, bufH, MROWS, C_, C_);

    for (int i = 0; i < L_; i++) {
        int m1 = 1 + 2 * i, m2 = 2 + 2 * i;
        k_mix_bf16<<<NSAMP / 2, 256, 0, stream>>>(bufH, adj, AhB);
        k_gemm_mfma<false><<<gg, 256, 0, stream>>>(
            AhB, WtH + (size_t)m1 * NPAD * C_,
            bres + (size_t)(2 * i) * C_, bn_res + (size_t)(2 * i) * 4 * C_,
            nullptr, bufX, MROWS, C_, C_);
        k_mix_bf16<<<NSAMP / 2, 256, 0, stream>>>(bufX, adj, AhB);
        k_gemm_mfma<true><<<gg, 256, 0, stream>>>(
            AhB, WtH + (size_t)m2 * NPAD * C_,
            bres + (size_t)(2 * i + 1) * C_, bn_res + (size_t)(2 * i + 1) * 4 * C_,
            bufH, bufH, MROWS, C_, C_);
    }

    k_pool<<<NSAMP, 256, 0, stream>>>(bufH, nhwc, center, featsB);

    k_gemm_mfma<false><<<gp, 256, 0, stream>>>(featsB, WpH, bp1, bn_pred,
                                               nullptr, bufP, NSAMP, C_, 3 * C_);

    k_final<<<(NSAMP * 2 * J_ + 255) / 256, 256, 0, stream>>>(bufP, Wp2, bp2, out);
}